// Round 7
// baseline (747.259 us; speedup 1.0000x reference)
//
#include <hip/hip_runtime.h>

#define BATCH 64
#define TT    1024
#define INC   16
#define NN    512
#define RNK   16
#define OUTC  8

// a = DT/TAU = 0.1
#define A_COEF 0.1f

__device__ __forceinline__ float fast_tanh(float x) {
    // tanh(x) = 1 - 2/(exp(2x)+1); safe at +/-inf
    float e = __expf(2.0f * x);
    return 1.0f - __fdividef(2.0f, e + 1.0f);
}

// Barrier with LDS ordering only (does NOT drain vmcnt: global stores are
// fire-and-forget, never read in-kernel).
__device__ __forceinline__ void lgkm_barrier() {
    asm volatile("s_waitcnt lgkmcnt(0)\n\ts_barrier" ::: "memory");
}

// Register pin: makes the value opaque to the compiler so it cannot
// rematerialize the originating load inside the loop (R6 failure: VGPR=52,
// all 32 weight-pairs reloaded from L1 every iteration).
#define PIN(v) asm volatile("" : "+v"(v))

// ---- DPP cross-lane ops (VALU pipe) ----
// quad_perm[1,0,3,2]=0xB1 (xor1), quad_perm[2,3,0,1]=0x4E (xor2),
// row_half_mirror=0x141 (xor7 within 16-row), row_ror:8=0x128 (xor8 within 16-row)
#define DPP_XOR1 0xB1
#define DPP_XOR2 0x4E
#define DPP_XOR7 0x141
#define DPP_XOR8 0x128
template<int CTRL>
__device__ __forceinline__ float dpp_mov(float x) {
    return __int_as_float(
        __builtin_amdgcn_update_dpp(0, __float_as_int(x), CTRL, 0xF, 0xF, true));
}

// ---- packed dual-FP32 FMA (VOP3P; exact f32 fma semantics) ----
__device__ __forceinline__ float2 pk_fma_blo(float2 a, float2 b, float2 c) {
    // d.lo = a.lo*b.lo + c.lo ; d.hi = a.hi*b.lo + c.hi   (broadcast b.lo)
    float2 d;
    asm("v_pk_fma_f32 %0, %1, %2, %3 op_sel_hi:[1,0,1]"
        : "=v"(d) : "v"(a), "v"(b), "v"(c));
    return d;
}
__device__ __forceinline__ float2 pk_fma_bhi(float2 a, float2 b, float2 c) {
    // broadcast b.hi
    float2 d;
    asm("v_pk_fma_f32 %0, %1, %2, %3 op_sel:[0,1,0] op_sel_hi:[1,1,1]"
        : "=v"(d) : "v"(a), "v"(b), "v"(c));
    return d;
}

// ---------------------------------------------------------------------------
// Fully fused: inp-projection + scan + out-projection in ONE kernel.
// 64 blocks x 256 threads, 1 batch/block, 2 states per lane.
//  - x[b] staged in LDS once (64 KB); per step 4 uniform b128 reads + 16
//    pk_fma compute inp inline (fills stall cycles; kills inp_kernel + Inp ws)
//  - V/U/In_w/Out_w weights in registers, PINNED against remat (R6 fix)
//  - low-rank path: R6-verified rho4 butterfly + 1 LDS write + 1 barrier +
//    4x b128 row-combine + DPP all-gather
//  - out path: R4-verified stages {1,2,7}+ror8 per 16-lane row -> LDS row
//    partials -> 8 duty lanes combine after the same barrier (out[t-1])
// Per step: 1 barrier, 2 LDS writes, ~8 LDS reads, 0 global loads.
// ---------------------------------------------------------------------------
__global__ __launch_bounds__(256, 1) void fused_kernel(
    const float* __restrict__ x,      // [B,T,INC]
    const float* __restrict__ In_w,   // [N,INC]
    const float* __restrict__ V_w,    // [R,N]
    const float* __restrict__ U_w,    // [N,R]
    const float* __restrict__ Out_w,  // [OUTC,N]
    const float* __restrict__ h0,     // [N]
    float* __restrict__ hidden,       // [B,T,N]
    float* __restrict__ out)          // [B,T,OUTC]
{
    const int tid = threadIdx.x;     // 0..255
    const int b   = blockIdx.x;
    const int n0  = tid << 1;        // states n0, n0+1
    const int row = tid >> 4;        // 0..15
    const int q4  = tid & 15;        // lane within 16-row

    // rho4: slot held after DPP stages {1,2,7,8} (R4/R6-verified)
    const int b0 = q4 & 1, b1 = (q4 >> 1) & 1, b2 = (q4 >> 2) & 1, b3 = (q4 >> 3) & 1;
    const int rho4 = ((b0 ^ b2) << 3) | ((b1 ^ b2) << 2) | (b2 << 1) | b3;
    // rho3: out-slot after stages {1,2,7} (R4-verified out_project algebra)
    const int rho3 = ((b0 ^ b2) << 2) | ((b1 ^ b2) << 1) | b2;

    __shared__ __align__(16) float xs[TT * INC];        // 64 KB: whole x[b]
    __shared__ __align__(16) float lowp[2][16][20];     // low row-partials
    __shared__ __align__(16) float outp[2][OUTC][20];   // out row-partials

    // ---- stage x[b] into LDS, coalesced float4 ----
    {
        const float4* src = (const float4*)(x + (size_t)b * TT * INC);
        float4* dst = (float4*)xs;
        #pragma unroll
        for (int cc = 0; cc < 16; ++cc)
            dst[cc * 256 + tid] = src[cc * 256 + tid];
    }

    // ---- weights in registers (rho-baked), then PINNED ----
    // Vpk[j][q] = (V[q^rho4][n0+j], V[(q^rho4)^8][n0+j])
    float2 Vpk[2][8];
    #pragma unroll
    for (int q = 0; q < 8; ++q) {
        const int rlo = q ^ rho4, rhi = rlo ^ 8;
        Vpk[0][q] = make_float2(V_w[rlo * NN + n0],     V_w[rhi * NN + n0]);
        Vpk[1][q] = make_float2(V_w[rlo * NN + n0 + 1], V_w[rhi * NN + n0 + 1]);
    }
    // Upk[s] = (U[n0][s^rho4], U[n0+1][s^rho4])
    float2 Upk[16];
    #pragma unroll
    for (int s = 0; s < 16; ++s)
        Upk[s] = make_float2(U_w[n0 * RNK + (s ^ rho4)],
                             U_w[(n0 + 1) * RNK + (s ^ rho4)]);
    // Wcol[i] = (In_w[n0][i], In_w[n0+1][i])
    float2 Wcol[INC];
    #pragma unroll
    for (int i = 0; i < INC; ++i)
        Wcol[i] = make_float2(In_w[n0 * INC + i], In_w[(n0 + 1) * INC + i]);
    // Opk[j][u] = (Ow[u^rho3][n0+j], Ow[(u^rho3)^4][n0+j])
    float2 Opk[2][4];
    #pragma unroll
    for (int u = 0; u < 4; ++u) {
        const int olo = u ^ rho3, ohi = olo ^ 4;
        Opk[0][u] = make_float2(Out_w[olo * NN + n0],     Out_w[ohi * NN + n0]);
        Opk[1][u] = make_float2(Out_w[olo * NN + n0 + 1], Out_w[ohi * NN + n0 + 1]);
    }

    // pin everything (112 VGPRs) so the compiler cannot sink/remat the loads
    #pragma unroll
    for (int q = 0; q < 8; ++q) {
        PIN(Vpk[0][q].x); PIN(Vpk[0][q].y); PIN(Vpk[1][q].x); PIN(Vpk[1][q].y);
    }
    #pragma unroll
    for (int s = 0; s < 16; ++s) { PIN(Upk[s].x); PIN(Upk[s].y); }
    #pragma unroll
    for (int i = 0; i < INC; ++i) { PIN(Wcol[i].x); PIN(Wcol[i].y); }
    #pragma unroll
    for (int u = 0; u < 4; ++u) {
        PIN(Opk[0][u].x); PIN(Opk[0][u].y); PIN(Opk[1][u].x); PIN(Opk[1][u].y);
    }

    float2 h = *(const float2*)&h0[n0];

    float* hb = hidden + (size_t)b * TT * NN;
    float* ob = out + (size_t)b * TT * OUTC;

    __syncthreads();  // xs staging visible

    const float2 z2 = make_float2(0.f, 0.f);

    for (int t = 0; t < TT; ++t) {
        // ---- x[t] from LDS (uniform broadcast, 4x b128) ----
        const float4* xp = (const float4*)(xs + t * INC);
        float4 xv0 = xp[0], xv1 = xp[1], xv2 = xp[2], xv3 = xp[3];

        // ---- phi = tanh(h) ----
        float2 phi = make_float2(fast_tanh(h.x), fast_tanh(h.y));

        // ---- V partials: Ppk[q] = (P[q], P[q+8]) ----
        float2 Ppk[8];
        #pragma unroll
        for (int q = 0; q < 8; ++q) {
            Ppk[q] = pk_fma_blo(Vpk[0][q], phi, z2);
            Ppk[q] = pk_fma_bhi(Vpk[1][q], phi, Ppk[q]);
        }

        // ---- out partials: opk[u] = (opart[u^rho3], opart[(u^rho3)^4]) ----
        float2 opk[4];
        #pragma unroll
        for (int u = 0; u < 4; ++u) {
            opk[u] = pk_fma_blo(Opk[0][u], phi, z2);
            opk[u] = pk_fma_bhi(Opk[1][u], phi, opk[u]);
        }

        // ---- inp = In_w . x[t] (independent; fills stalls) ----
        float2 ipk;
        {
            float2 xp0 = make_float2(xv0.x, xv0.y);
            float2 xp1 = make_float2(xv0.z, xv0.w);
            float2 xp2 = make_float2(xv1.x, xv1.y);
            float2 xp3 = make_float2(xv1.z, xv1.w);
            float2 xp4 = make_float2(xv2.x, xv2.y);
            float2 xp5 = make_float2(xv2.z, xv2.w);
            float2 xp6 = make_float2(xv3.x, xv3.y);
            float2 xp7 = make_float2(xv3.z, xv3.w);
            float2 iA = pk_fma_blo(Wcol[0], xp0, z2);
            iA = pk_fma_bhi(Wcol[1],  xp0, iA);
            float2 iB = pk_fma_blo(Wcol[2], xp1, z2);
            iB = pk_fma_bhi(Wcol[3],  xp1, iB);
            iA = pk_fma_blo(Wcol[4],  xp2, iA);
            iA = pk_fma_bhi(Wcol[5],  xp2, iA);
            iB = pk_fma_blo(Wcol[6],  xp3, iB);
            iB = pk_fma_bhi(Wcol[7],  xp3, iB);
            iA = pk_fma_blo(Wcol[8],  xp4, iA);
            iA = pk_fma_bhi(Wcol[9],  xp4, iA);
            iB = pk_fma_blo(Wcol[10], xp5, iB);
            iB = pk_fma_bhi(Wcol[11], xp5, iB);
            iA = pk_fma_blo(Wcol[12], xp6, iA);
            iA = pk_fma_bhi(Wcol[13], xp6, iA);
            iB = pk_fma_blo(Wcol[14], xp7, iB);
            iB = pk_fma_bhi(Wcol[15], xp7, iB);
            ipk = make_float2(iA.x + iB.x, iA.y + iB.y);
        }

        // ---- low reduce-scatter within 16-lane row (R6-verified) ----
        #pragma unroll
        for (int q = 0; q < 8; ++q) Ppk[q].x += dpp_mov<DPP_XOR1>(Ppk[q].y);
        #pragma unroll
        for (int s = 0; s < 4; ++s) Ppk[s].x += dpp_mov<DPP_XOR2>(Ppk[s + 4].x);
        Ppk[0].x += dpp_mov<DPP_XOR7>(Ppk[2].x);
        Ppk[1].x += dpp_mov<DPP_XOR7>(Ppk[3].x);
        Ppk[0].x += dpp_mov<DPP_XOR8>(Ppk[1].x);
        lowp[t & 1][rho4][row] = Ppk[0].x;

        // ---- out reduce within 16-lane row (R4-verified stages) ----
        #pragma unroll
        for (int u = 0; u < 4; ++u) opk[u].x += dpp_mov<DPP_XOR1>(opk[u].y);
        opk[0].x += dpp_mov<DPP_XOR2>(opk[2].x);
        opk[1].x += dpp_mov<DPP_XOR2>(opk[3].x);
        opk[0].x += dpp_mov<DPP_XOR7>(opk[1].x);
        opk[0].x += dpp_mov<DPP_XOR8>(opk[0].x);   // row16 sum, dup in halves
        if (q4 < 8) outp[t & 1][rho3][row] = opk[0].x;

        lgkm_barrier();   // the ONLY barrier per step

        // ---- combine 16 low row-partials (4x b128 + tree) ----
        const float4* lp = (const float4*)&lowp[t & 1][rho4][0];
        float4 s0 = lp[0], s1 = lp[1], s2 = lp[2], s3 = lp[3];
        float e0 = (s0.x + s1.x) + (s2.x + s3.x);
        float e1 = (s0.y + s1.y) + (s2.y + s3.y);
        float e2 = (s0.z + s1.z) + (s2.z + s3.z);
        float e3 = (s0.w + s1.w) + (s2.w + s3.w);
        float L = (e0 + e1) + (e2 + e3);     // low[rho4]

        // ---- all-gather (R4-verified): G[s] = low[s ^ rho4] ----
        float g0 = L;
        float g1 = dpp_mov<DPP_XOR8>(g0);
        float g2 = dpp_mov<DPP_XOR7>(g0);
        float g3 = dpp_mov<DPP_XOR7>(g1);
        float g4 = dpp_mov<DPP_XOR2>(g0);
        float g5 = dpp_mov<DPP_XOR2>(g1);
        float g6 = dpp_mov<DPP_XOR2>(g2);
        float g7 = dpp_mov<DPP_XOR2>(g3);
        float2 Gp[8];
        Gp[0] = make_float2(g0, g1);
        Gp[1] = make_float2(g2, g3);
        Gp[2] = make_float2(g4, g5);
        Gp[3] = make_float2(g6, g7);
        Gp[4] = make_float2(dpp_mov<DPP_XOR1>(g0), dpp_mov<DPP_XOR1>(g1));
        Gp[5] = make_float2(dpp_mov<DPP_XOR1>(g2), dpp_mov<DPP_XOR1>(g3));
        Gp[6] = make_float2(dpp_mov<DPP_XOR1>(g4), dpp_mov<DPP_XOR1>(g5));
        Gp[7] = make_float2(dpp_mov<DPP_XOR1>(g6), dpp_mov<DPP_XOR1>(g7));

        // ---- rec = inp + U . low (one complete pass, R6-verified) ----
        float2 recA = ipk, recB = z2;
        #pragma unroll
        for (int u = 0; u < 8; u += 2) {
            recA = pk_fma_blo(Upk[2 * u],     Gp[u],     recA);
            recA = pk_fma_bhi(Upk[2 * u + 1], Gp[u],     recA);
            recB = pk_fma_blo(Upk[2 * u + 2], Gp[u + 1], recB);
            recB = pk_fma_bhi(Upk[2 * u + 3], Gp[u + 1], recB);
        }
        float2 rec = make_float2(recA.x + recB.x, recA.y + recB.y);

        // ---- h update + store ----
        h.x = fmaf(A_COEF, rec.x - h.x, h.x);
        h.y = fmaf(A_COEF, rec.y - h.y, h.y);
        ((float2*)(hb + (size_t)t * NN))[tid] = h;   // fire-and-forget

        // ---- out[t-1] combine: 8 duty lanes, off critical path ----
        if (t > 0 && tid < 8) {
            const float4* op = (const float4*)&outp[t & 1][tid][0];
            float4 o0 = op[0], o1 = op[1], o2 = op[2], o3 = op[3];
            float f0 = (o0.x + o1.x) + (o2.x + o3.x);
            float f1 = (o0.y + o1.y) + (o2.y + o3.y);
            float f2 = (o0.z + o1.z) + (o2.z + o3.z);
            float f3 = (o0.w + o1.w) + (o2.w + o3.w);
            ob[(size_t)(t - 1) * OUTC + tid] = (f0 + f1) + (f2 + f3);
        }
    }

    // ---- epilogue: out[TT-1] from tanh(final h) ----
    {
        float2 phi = make_float2(fast_tanh(h.x), fast_tanh(h.y));
        float2 opk[4];
        #pragma unroll
        for (int u = 0; u < 4; ++u) {
            opk[u] = pk_fma_blo(Opk[0][u], phi, z2);
            opk[u] = pk_fma_bhi(Opk[1][u], phi, opk[u]);
        }
        #pragma unroll
        for (int u = 0; u < 4; ++u) opk[u].x += dpp_mov<DPP_XOR1>(opk[u].y);
        opk[0].x += dpp_mov<DPP_XOR2>(opk[2].x);
        opk[1].x += dpp_mov<DPP_XOR2>(opk[3].x);
        opk[0].x += dpp_mov<DPP_XOR7>(opk[1].x);
        opk[0].x += dpp_mov<DPP_XOR8>(opk[0].x);
        if (q4 < 8) outp[TT & 1][rho3][row] = opk[0].x;
        lgkm_barrier();
        if (tid < 8) {
            const float4* op = (const float4*)&outp[TT & 1][tid][0];
            float4 o0 = op[0], o1 = op[1], o2 = op[2], o3 = op[3];
            float f0 = (o0.x + o1.x) + (o2.x + o3.x);
            float f1 = (o0.y + o1.y) + (o2.y + o3.y);
            float f2 = (o0.z + o1.z) + (o2.z + o3.z);
            float f3 = (o0.w + o1.w) + (o2.w + o3.w);
            ob[(size_t)(TT - 1) * OUTC + tid] = (f0 + f1) + (f2 + f3);
        }
    }
}

extern "C" void kernel_launch(void* const* d_in, const int* in_sizes, int n_in,
                              void* d_out, int out_size, void* d_ws, size_t ws_size,
                              hipStream_t stream) {
    const float* x    = (const float*)d_in[0];  // [64,1024,16]
    const float* In_w = (const float*)d_in[1];  // [512,16]
    const float* V_w  = (const float*)d_in[2];  // [16,512]
    const float* U_w  = (const float*)d_in[3];  // [512,16]
    const float* Ow   = (const float*)d_in[4];  // [8,512]
    const float* h0   = (const float*)d_in[5];  // [512]

    float* hidden = (float*)d_out;                         // [64,1024,512]
    float* out    = hidden + (size_t)BATCH * TT * NN;      // [64,1024,8]

    // One fully fused kernel: 64 blocks x 256 threads, 1 batch per block.
    fused_kernel<<<BATCH, 256, 0, stream>>>(x, In_w, V_w, U_w, Ow, h0,
                                            hidden, out);
}